// Round 1
// 1484.183 us; speedup vs baseline: 1.8291x; 1.8291x over previous
//
#include <hip/hip_runtime.h>
#include <cstdint>
#include <cstddef>

// HardNegativeMining: B=2048 rows, N=100000 candidates, k=128 outputs/row.
// out_logits[row] = [logits[pos], top-127 of remaining logits desc]
// out_labels[row] = [1, 0, ..., 0]
//
// Fully fused single-kernel design: one persistent block per row.
//  - Stream logits+labels once (float4, coalesced), threshold z=2.5 -> ~621 cand/row.
//  - Candidates (VALUES only -- indices are unnecessary: output is values, and the
//    positive can be excluded by removing one occurrence of posVal) appended to LDS
//    via LDS-scope atomics (no device-scope atomic round-trip, no global cand buffer).
//  - pos/posVal captured in-flight: the thread seeing the nonzero label holds the logit.
//  - Bitonic sort 1024 in LDS, emit. Slow path covers pathological rows (never hit
//    on iid-normal bench data).

#define N_CAND 100000
#define KOUT 128
#define THRESH 2.5f
#define SORT_N 1024
#define NT 512
#define NW (NT / 64)

__global__ __launch_bounds__(NT, 8) void hnm_fused(
    const float* __restrict__ logits,
    const float* __restrict__ labels,
    float* __restrict__ outLogits,
    float* __restrict__ outLabels)
{
    __shared__ float sv[SORT_N];
    __shared__ int   sCnt;
    __shared__ int   sPos;
    __shared__ float sPosVal;
    __shared__ int   sExcl;
    __shared__ float swv[NW];
    __shared__ int   swi[NW];
    __shared__ float sbv;
    __shared__ int   sbi;

    const int row = blockIdx.x;
    const int tid = threadIdx.x;

    if (tid == 0) { sCnt = 0; sPos = -1; sPosVal = 0.f; sExcl = 0x7fffffff; }
    __syncthreads();

    const float4* Lg = (const float4*)(logits + (size_t)row * N_CAND);
    const float4* Lb = (const float4*)(labels + (size_t)row * N_CAND);
    const int M = N_CAND / 4;  // 25000, exact (N_CAND % 4 == 0)

    // ---- fused streaming scan: candidates + positive detection ----
    #pragma unroll 2
    for (int i = tid; i < M; i += NT) {
        const float4 lg = Lg[i];
        const float4 lb = Lb[i];

        // one-hot labels: exactly one nonzero per row -> single writer, plain LDS store
        if (lb.x != 0.f) { sPos = 4 * i + 0; sPosVal = lg.x; }
        if (lb.y != 0.f) { sPos = 4 * i + 1; sPosVal = lg.y; }
        if (lb.z != 0.f) { sPos = 4 * i + 2; sPosVal = lg.z; }
        if (lb.w != 0.f) { sPos = 4 * i + 3; sPosVal = lg.w; }

        const int c = (lg.x > THRESH) + (lg.y > THRESH) + (lg.z > THRESH) + (lg.w > THRESH);
        if (c) {  // ~2.5% of iterations; LDS-scope atomic (ds_add_rtn), cheap
            int b = atomicAdd(&sCnt, c);
            const float v[4] = {lg.x, lg.y, lg.z, lg.w};
            #pragma unroll
            for (int j = 0; j < 4; ++j) {
                if (v[j] > THRESH) {
                    if (b < SORT_N) sv[b] = v[j];
                    ++b;
                }
            }
        }
    }
    __syncthreads();

    const int count = sCnt;
    int   pos    = sPos;
    float posVal = sPosVal;
    if (pos < 0) {  // safety: all-zero labels (never on bench data)
        pos = 0;
        posVal = logits[(size_t)row * N_CAND];
    }

    float* oL = outLogits + (size_t)row * KOUT;
    float* oB = outLabels + (size_t)row * KOUT;

    if (count >= KOUT && count <= SORT_N) {
        // ---- fast path: every value > THRESH captured; >=127 negatives remain after
        // excluding one occurrence of posVal (entries == posVal exist iff posVal > THRESH;
        // ties with other columns are value-identical, so removing any one is exact).
        for (int i = tid; i < SORT_N; i += NT) {
            if (i >= count)             sv[i] = -INFINITY;       // pad
            else if (sv[i] == posVal)   atomicMin(&sExcl, i);    // find one positive slot
        }
        __syncthreads();
        if (tid == 0 && sExcl < count) sv[sExcl] = -INFINITY;
        __syncthreads();

        // bitonic sort, descending
        for (int k = 2; k <= SORT_N; k <<= 1) {
            for (int j = k >> 1; j > 0; j >>= 1) {
                #pragma unroll
                for (int i = tid; i < SORT_N; i += NT) {
                    const int ixj = i ^ j;
                    if (ixj > i) {
                        const float a = sv[i], b = sv[ixj];
                        if (((i & k) == 0) ? (a < b) : (a > b)) { sv[i] = b; sv[ixj] = a; }
                    }
                }
                __syncthreads();
            }
        }

        if (tid < KOUT) {
            oL[tid] = (tid == 0) ? posVal : sv[tid - 1];
            oB[tid] = (tid == 0) ? 1.0f : 0.0f;
        }
    } else {
        // ---- slow path (general correctness; never hit on iid-normal bench data):
        // 127 rounds of block-wide lexicographic max over the raw row.
        if (tid < KOUT) oB[tid] = (tid == 0) ? 1.0f : 0.0f;
        if (tid == 0)   oL[0]  = posVal;

        const float* rowp = logits + (size_t)row * N_CAND;
        float prevV = INFINITY;
        int   prevI = -1;
        const int wid  = tid >> 6;
        const int lane = tid & 63;

        for (int r = 0; r < KOUT - 1; ++r) {
            float bv = -INFINITY;
            int   bi = 0x7fffffff;
            for (int i = tid; i < N_CAND; i += NT) {
                if (i == pos) continue;
                const float v = rowp[i];
                const bool elig = (v < prevV) || (v == prevV && i > prevI);
                if (elig && (v > bv || (v == bv && i < bi))) { bv = v; bi = i; }
            }
            #pragma unroll
            for (int d = 32; d > 0; d >>= 1) {
                const float ov = __shfl_down(bv, d, 64);
                const int   oi = __shfl_down(bi, d, 64);
                if (ov > bv || (ov == bv && oi < bi)) { bv = ov; bi = oi; }
            }
            if (lane == 0) { swv[wid] = bv; swi[wid] = bi; }
            __syncthreads();
            if (tid == 0) {
                #pragma unroll
                for (int w = 1; w < NW; ++w) {
                    if (swv[w] > bv || (swv[w] == bv && swi[w] < bi)) { bv = swv[w]; bi = swi[w]; }
                }
                sbv = bv; sbi = bi;
                oL[1 + r] = bv;
            }
            __syncthreads();
            prevV = sbv;
            prevI = sbi;
        }
    }
}

extern "C" void kernel_launch(void* const* d_in, const int* in_sizes, int n_in,
                              void* d_out, int out_size, void* d_ws, size_t ws_size,
                              hipStream_t stream) {
    const float* logits = (const float*)d_in[0];
    const float* labels = (const float*)d_in[1];
    const int B = in_sizes[0] / N_CAND;  // 2048

    float* outLogits = (float*)d_out;
    float* outLabels = outLogits + (size_t)B * KOUT;

    // No workspace, no memset, one launch: everything lives in LDS.
    hnm_fused<<<B, NT, 0, stream>>>(logits, labels, outLogits, outLabels);
}